// Round 10
// baseline (133.248 us; speedup 1.0000x reference)
//
#include <hip/hip_runtime.h>
#include <math.h>

#define NRAYS 8192
#define T 128
#define H 128
#define SHD 16

using short8 = __attribute__((ext_vector_type(8))) short;
using f32x4  = __attribute__((ext_vector_type(4))) float;
using f32x2  = __attribute__((ext_vector_type(2))) float;
using u32x2  = __attribute__((ext_vector_type(2))) unsigned;

__device__ __forceinline__ float fexp(float x) {
  return exp2f(x * 1.44269504088896341f);
}
__device__ __forceinline__ float softplus_f(float x) {
  return fmaxf(x, 0.f) + 0.693147180559945309f * log2f(1.f + fexp(-fabsf(x)));
}
__device__ __forceinline__ float sigmoid_f(float x) {
  return __builtin_amdgcn_rcpf(1.f + fexp(-x));
}

// RNE float->bf16 (preprocess only)
__device__ __forceinline__ unsigned f2bf(float f) {
  unsigned u = __float_as_uint(f);
  return (u + 0x7fffu + ((u >> 16) & 1u)) >> 16;
}

// round-half-up bf16 pack of a float pair: v_pk_add_u32 + v_perm (2 VALU)
__device__ __forceinline__ unsigned pk2(f32x2 h) {
  const u32x2 u = __builtin_bit_cast(u32x2, h) + (u32x2){0x8000u, 0x8000u};
  return __builtin_amdgcn_perm(u[1], u[0], 0x07060302u);
}

// DPP add: v += dpp_mov(v) with compile-time ctrl/row_mask; old=0 so masked/OOB add 0.
template<int CTRL, int RM>
__device__ __forceinline__ float dppadd(float v) {
  const int t = __builtin_amdgcn_update_dpp(0, __builtin_bit_cast(int, v), CTRL, RM, 0xf, false);
  return v + __builtin_bit_cast(float, t);
}
// 64-lane inclusive scan, pure DPP (no LDS pipe)
__device__ __forceinline__ float wave_iscan(float v) {
  v = dppadd<0x111, 0xf>(v);   // row_shr:1
  v = dppadd<0x112, 0xf>(v);   // row_shr:2
  v = dppadd<0x114, 0xf>(v);   // row_shr:4
  v = dppadd<0x118, 0xf>(v);   // row_shr:8
  v = dppadd<0x142, 0xa>(v);   // row_bcast15 -> rows 1,3
  v = dppadd<0x143, 0xc>(v);   // row_bcast31 -> rows 2,3
  return v;
}
__device__ __forceinline__ float wave_total(float v) {   // broadcast of 64-lane sum
  v = wave_iscan(v);
  return __builtin_bit_cast(float, __builtin_amdgcn_readlane(__builtin_bit_cast(int, v), 63));
}

// ---- preprocess (unchanged from R9) ----
__global__ void preprocess(const float* __restrict__ W2, const float* __restrict__ Wd,
                           const float* __restrict__ Wc, const float* __restrict__ bc,
                           const float* __restrict__ origins, const float* __restrict__ dirs,
                           unsigned short* __restrict__ w2t,
                           unsigned short* __restrict__ woutf,
                           float* __restrict__ rayp_all) {
  const int t = blockIdx.x * 256 + threadIdx.x;
  if (t < 16384) {
    const int n = t >> 7, p = t & 127;
    const int o = (p >> 3) ^ (n & 7);
    const int k = o * 8 + (p & 7);
    w2t[t] = (unsigned short)f2bf(W2[k * 128 + n]);
  }
  if (t < 2048) {
    const int kk = t >> 9, L = (t >> 3) & 63, j = t & 7;
    const int c = L & 15, g = L >> 4;
    const int k = kk * 32 + g * 8 + j;
    float v = 0.f;
    if (c == 0) v = Wd[k];
    else if (c < 4) v = Wc[k * 3 + (c - 1)];
    woutf[t] = (unsigned short)f2bf(v);
  }
  if (t < NRAYS) {
    const float ox = origins[t*3+0], oy = origins[t*3+1], oz = origins[t*3+2];
    const float dx = dirs[t*3+0],  dy = dirs[t*3+1],  dz = dirs[t*3+2];
    const float ix = 1.f/dx, iy = 1.f/dy, iz = 1.f/dz;
    const float t1x = (-1.f-ox)*ix, t2x = (1.f-ox)*ix;
    const float t1y = (-1.f-oy)*iy, t2y = (1.f-oy)*iy;
    const float t1z = (-1.f-oz)*iz, t2z = (1.f-oz)*iz;
    float tnear = fmaxf(fmaxf(fminf(t1x,t2x), fminf(t1y,t2y)), fminf(t1z,t2z));
    tnear = fmaxf(tnear, 0.f);
    const float tfar = fminf(fminf(fmaxf(t1x,t2x), fmaxf(t1y,t2y)), fmaxf(t1z,t2z));
    const bool  active = tfar > tnear;
    const float tfar_c = fmaxf(tfar, tnear + 1e-3f);
    const float dnorm = sqrtf(dx*dx + dy*dy + dz*dz);
    const float nx = dx/dnorm, ny = dy/dnorm, nz = dz/dnorm;
    const float x2 = nx*nx, y2 = ny*ny, z2 = nz*nz;
    const float xy = nx*ny, yz = ny*nz, xz = nx*nz;
    float ynm[16];
    ynm[0]  = 0.282094791773878f;
    ynm[1]  = -0.48860251190292f*ny;
    ynm[2]  = 0.48860251190292f*nz;
    ynm[3]  = -0.48860251190292f*nx;
    ynm[4]  = 1.0925484305920792f*xy;
    ynm[5]  = -1.0925484305920792f*yz;
    ynm[6]  = 0.94617469575756f*z2 - 0.31539156525252f;
    ynm[7]  = -1.0925484305920792f*xz;
    ynm[8]  = 0.5462742152960396f*(x2-y2);
    ynm[9]  = 0.5900435899266435f*ny*(-3.f*x2+y2);
    ynm[10] = 2.8906114426405538f*xy*nz;
    ynm[11] = 0.4570457994644658f*ny*(1.f-5.f*z2);
    ynm[12] = 0.3731763325901154f*nz*(5.f*z2-3.f);
    ynm[13] = 0.4570457994644658f*nx*(1.f-5.f*z2);
    ynm[14] = 1.445305721320277f*nz*(x2-y2);
    ynm[15] = 0.5900435899266435f*nx*(-x2+3.f*y2);
    float cp0 = bc[0], cp1 = bc[1], cp2 = bc[2];
    #pragma unroll
    for (int s = 0; s < SHD; ++s) {
      cp0 = fmaf(ynm[s], Wc[(H+s)*3+0], cp0);
      cp1 = fmaf(ynm[s], Wc[(H+s)*3+1], cp1);
      cp2 = fmaf(ynm[s], Wc[(H+s)*3+2], cp2);
    }
    rayp_all[t*8+0] = tfar_c;
    rayp_all[t*8+1] = dnorm;
    rayp_all[t*8+2] = active ? 1.f : 0.f;
    rayp_all[t*8+3] = cp0;
    rayp_all[t*8+4] = cp1;
    rayp_all[t*8+5] = cp2;
    rayp_all[t*8+6] = tnear;
    rayp_all[t*8+7] = 0.f;
  }
}

// One ray/block. 2x2 wave split: wave (wh=w>>1, ws=w&1) owns hidden [64wh,64wh+64)
// x samples [64ws,64ws+64). acc[tn][mi] = 64 AGPRs (same as R9).
__global__ __launch_bounds__(256, 4) void nerf_render(
    const float* __restrict__ origins, const float* __restrict__ dirs,
    const float* __restrict__ u, const float* __restrict__ W1,
    const float* __restrict__ b1, const float* __restrict__ b2,
    const float* __restrict__ bd, const unsigned short* __restrict__ w2t,
    const unsigned short* __restrict__ woutf, const float* __restrict__ rayp_all,
    float* __restrict__ out)
{
  const int ray = blockIdx.x;
  const int tid = threadIdx.x;
  const int L = tid & 63;
  const int w = tid >> 6;
  const int wh = w >> 1;           // hidden half
  const int ws = w & 1;            // sample half
  const int g = L >> 4;
  const int c = L & 15;

  __shared__ __align__(16) short Bs[16384];       // swizzled W2^T; head aliased as SredH later
  __shared__ __align__(16) short As2[4 * 640];    // per-wave epilogue slab
  __shared__ __align__(16) float baseA[H];        // affine layer-1 SoA
  __shared__ __align__(16) float slopeA[H];
  __shared__ float ts_s[T];
  __shared__ float mask_s[T];
  __shared__ float wred[2][4];
  __shared__ float wtot[2];

  // per-ray scalars (wave-uniform -> scalar loads)
  const float tfar_c = rayp_all[ray*8+0];
  const float dnorm  = rayp_all[ray*8+1];
  const float actf   = rayp_all[ray*8+2];
  const float cpo0   = rayp_all[ray*8+3];
  const float cpo1   = rayp_all[ray*8+4];
  const float cpo2   = rayp_all[ray*8+5];
  const float tnear  = rayp_all[ray*8+6];

  // ---- stage W2 (LDS), proven float4 path ----
  {
    const float4* src = (const float4*)w2t;
    float4* dst = (float4*)Bs;
    #pragma unroll
    for (int i = 0; i < 8; ++i) dst[tid + i * 256] = src[tid + i * 256];
  }

  // ---- per-sample setup (tid<128): samples + affine layer-1 coefficients ----
  if (tid < T) {
    const int tl = tid;
    const float ox = origins[ray*3+0], oy = origins[ray*3+1], oz = origins[ray*3+2];
    const float dx = dirs[ray*3+0],  dy = dirs[ray*3+1],  dz = dirs[ray*3+2];
    const bool active = actf != 0.f;
    const float ut = u[ray*T + tl];
    const float frac = ((float)tl + ut) * (1.f/(float)T);
    const float tt = tnear + (tfar_c - tnear) * frac;
    const float px = fmaf(dx, tt, ox);
    const float py = fmaf(dy, tt, oy);
    const float pz = fmaf(dz, tt, oz);
    ts_s[tl] = tt;
    const bool m = (fabsf(px) <= 1.f) && (fabsf(py) <= 1.f) && (fabsf(pz) <= 1.f) && active;
    mask_s[tl] = m ? 1.f : 0.f;
    const float w0 = W1[tl], w1v = W1[H + tl], w2v = W1[2*H + tl];
    baseA[tl]  = fmaf(ox, w0, fmaf(oy, w1v, fmaf(oz, w2v, b1[tl])));
    slopeA[tl] = fmaf(dx, w0, fmaf(dy, w1v, dz * w2v));
  }

  // ---- acc init = b2 (uniform global reads, L2-hot); mt = wh*4+mi ----
  f32x4 acc[4][4];   // [tn][mi]
  #pragma unroll
  for (int mi = 0; mi < 4; ++mi) {
    const float4 bv = *(const float4*)&b2[(wh*4 + mi)*16 + g*4];
    #pragma unroll
    for (int tn = 0; tn < 4; ++tn) {
      acc[tn][mi][0] = bv.x; acc[tn][mi][1] = bv.y;
      acc[tn][mi][2] = bv.z; acc[tn][mi][3] = bv.w;
    }
  }
  __syncthreads();

  // sample t-values for this wave's 4 sample-tiles
  float t_tn[4];
  #pragma unroll
  for (int tn = 0; tn < 4; ++tn) t_tn[tn] = ts_s[64*ws + 16*tn + c];

  const f32x2 zero2 = {0.f, 0.f};

  // ---- K-loop: affine layer1 (packed VALU, 4 sample-tiles) + layer2 MFMA ----
  #pragma unroll
  for (int ks = 0; ks < 4; ++ks) {
    const int kb = ks*32 + g*8;
    const f32x4 bq0 = *(const f32x4*)&baseA[kb];
    const f32x4 bq1 = *(const f32x4*)&baseA[kb+4];
    const f32x4 sq0 = *(const f32x4*)&slopeA[kb];
    const f32x4 sq1 = *(const f32x4*)&slopeA[kb+4];
    const f32x2 b01 = {bq0[0], bq0[1]}, b23 = {bq0[2], bq0[3]};
    const f32x2 b45 = {bq1[0], bq1[1]}, b67 = {bq1[2], bq1[3]};
    const f32x2 s01 = {sq0[0], sq0[1]}, s23 = {sq0[2], sq0[3]};
    const f32x2 s45 = {sq1[0], sq1[1]}, s67 = {sq1[2], sq1[3]};

    // preload this wave's 4 W2 A-frags (reused across 4 sample-tiles)
    const int swb = ((ks*4 + g) ^ (c & 7)) * 8;   // swizzled octet (conflict-free)
    short8 wf[4];
    #pragma unroll
    for (int mi = 0; mi < 4; ++mi)
      wf[mi] = *(const short8*)&Bs[((wh*4 + mi)*16 + c)*128 + swb];

    #pragma unroll
    for (int tn = 0; tn < 4; ++tn) {
      const f32x2 t2 = {t_tn[tn], t_tn[tn]};
      const f32x2 a01 = __builtin_elementwise_max(__builtin_elementwise_fma(t2, s01, b01), zero2);
      const f32x2 a23 = __builtin_elementwise_max(__builtin_elementwise_fma(t2, s23, b23), zero2);
      const f32x2 a45 = __builtin_elementwise_max(__builtin_elementwise_fma(t2, s45, b45), zero2);
      const f32x2 a67 = __builtin_elementwise_max(__builtin_elementwise_fma(t2, s67, b67), zero2);
      union U { uint4 u; short8 s; } Bf;
      Bf.u = make_uint4(pk2(a01), pk2(a23), pk2(a45), pk2(a67));
      #pragma unroll
      for (int mi = 0; mi < 4; ++mi)
        acc[tn][mi] = __builtin_amdgcn_mfma_f32_16x16x32_bf16(wf[mi], Bf.s, acc[tn][mi], 0, 0, 0);
    }
  }
  __syncthreads();   // all waves done with Bs -> safe to alias SredH onto it
  float4* SredH = (float4*)Bs;   // [2][128] {sigma_pre, cp0, cp1, cp2} hidden-half partials

  // ---- epilogue: relu -> bf16 slab -> 2-k-step MFMA dot with this wave's Wout slice ----
  short* As2w = As2 + w * 640;
  short8 wa2[2];
  #pragma unroll
  for (int i = 0; i < 2; ++i)
    wa2[i] = *(const short8*)&woutf[((2*wh + i)*64 + L)*8];   // global, L2-hot

  #pragma unroll
  for (int tn = 0; tn < 4; ++tn) {
    f32x4 oacc;
    oacc[0] = 0.f; oacc[1] = 0.f; oacc[2] = 0.f; oacc[3] = 0.f;
    #pragma unroll
    for (int i = 0; i < 2; ++i) {
      #pragma unroll
      for (int q = 0; q < 2; ++q) {
        const int mi = 2*i + q;
        const f32x4 a = acc[tn][mi];
        const f32x2 h01 = __builtin_elementwise_max((f32x2){a[0], a[1]}, zero2);
        const f32x2 h23 = __builtin_elementwise_max((f32x2){a[2], a[3]}, zero2);
        *(uint2*)&As2w[c*40 + q*16 + g*4] = make_uint2(pk2(h01), pk2(h23));
      }
      const short8 hbf = *(const short8*)&As2w[c*40 + g*8];
      oacc = __builtin_amdgcn_mfma_f32_16x16x32_bf16(wa2[i], hbf, oacc, 0, 0, 0);
    }
    if (g == 0)   // lane holds partial {sigma,c0,c1,c2} for sample 64ws+16tn+c
      SredH[wh*128 + 64*ws + 16*tn + c] = make_float4(oacc[0], oacc[1], oacc[2], oacc[3]);
  }
  __syncthreads();

  // ---- per-sample activations + transmittance (tid<128): sum hidden-half partials ----
  float sd = 0.f, cc0 = 0.f, cc1 = 0.f, cc2 = 0.f;
  if (tid < T) {
    const float4 sv0 = SredH[tid];
    const float4 sv1 = SredH[128 + tid];
    const float mk = mask_s[tid];
    const float sigma = softplus_f(sv0.x + sv1.x + bd[0]) * mk;
    cc0 = mk * sigmoid_f(sv0.y + sv1.y + cpo0);
    cc1 = mk * sigmoid_f(sv0.z + sv1.z + cpo1);
    cc2 = mk * sigmoid_f(sv0.w + sv1.w + cpo2);
    const float tt = ts_s[tid];
    const float tnext = (tid < T-1) ? ts_s[tid + 1] : tfar_c * 10.f;
    sd = sigma * (tnext - tt) * dnorm;
  }

  // ---- inclusive scan: DPP in-wave + cross-wave stitch ----
  const float val = wave_iscan(sd);
  if (tid < T && L == 63) wtot[w] = val;
  __syncthreads();
  const float csum = val + ((w == 1) ? wtot[0] : 0.f);

  // ---- weights + per-ray reduction (DPP totals, no LDS shuffles) ----
  float wgt = 0.f, wcx = 0.f, wcy = 0.f, wcz = 0.f;
  if (tid < T) {
    wgt = fexp(sd - csum) - fexp(-csum);
    wcx = wgt * cc0; wcy = wgt * cc1; wcz = wgt * cc2;
  }
  const float swgt = wave_total(wgt);
  const float swcx = wave_total(wcx);
  const float swcy = wave_total(wcy);
  const float swcz = wave_total(wcz);
  if (tid < T && L == 0) {
    wred[w][0] = swgt; wred[w][1] = swcx; wred[w][2] = swcy; wred[w][3] = swcz;
  }
  __syncthreads();
  if (tid == 0) {
    const float aw = wred[0][0] + wred[1][0];
    const float o0 = wred[0][1] + wred[1][1];
    const float o1 = wred[0][2] + wred[1][2];
    const float o2 = wred[0][3] + wred[1][3];
    const bool act = actf != 0.f;
    out[ray*4+0] = act ? o0 : 0.f;
    out[ray*4+1] = act ? o1 : 0.f;
    out[ray*4+2] = act ? o2 : 0.f;
    out[ray*4+3] = act ? aw : 0.f;
  }
}

extern "C" void kernel_launch(void* const* d_in, const int* in_sizes, int n_in,
                              void* d_out, int out_size, void* d_ws, size_t ws_size,
                              hipStream_t stream) {
  const float* origins = (const float*)d_in[0];
  const float* dirs    = (const float*)d_in[1];
  const float* u       = (const float*)d_in[2];
  const float* W1      = (const float*)d_in[3];
  const float* b1      = (const float*)d_in[4];
  const float* W2      = (const float*)d_in[5];
  const float* b2      = (const float*)d_in[6];
  const float* Wd      = (const float*)d_in[7];
  const float* bd      = (const float*)d_in[8];
  const float* Wc      = (const float*)d_in[9];
  const float* bc      = (const float*)d_in[10];

  unsigned short* w2t      = (unsigned short*)d_ws;
  unsigned short* woutf    = (unsigned short*)((char*)d_ws + 32768);
  float*          rayp_all = (float*)((char*)d_ws + 36864);

  preprocess<<<64, 256, 0, stream>>>(W2, Wd, Wc, bc, origins, dirs,
                                     w2t, woutf, rayp_all);
  nerf_render<<<NRAYS, 256, 0, stream>>>(origins, dirs, u, W1, b1, b2, bd,
                                         w2t, woutf, rayp_all, (float*)d_out);
}